// Round 1
// baseline (1061.308 us; speedup 1.0000x reference)
//
#include <hip/hip_runtime.h>
#include <hip/hip_bf16.h>

#define BATCH 4
#define CCH 256
#define TLEN 8192
#define LAYERS 10
#define BCT (BATCH*CCH*TLEN)   // 8,388,608 elements
#define TPAD 1024              // causal zero-pad rows per batch (max shift = 2*512)
#define TROWS (TPAD + TLEN)    // 9216

typedef __attribute__((ext_vector_type(8))) short bf16x8;
typedef __attribute__((ext_vector_type(4))) float f32x4;

__device__ __forceinline__ unsigned short f2b(float f) {
  union { float f; unsigned u; } v; v.f = f;
  unsigned r = (v.u + 0x7FFFu + ((v.u >> 16) & 1u)) >> 16;
  return (unsigned short)r;
}
__device__ __forceinline__ float b2f(unsigned short h) {
  union { unsigned u; float f; } v; v.u = ((unsigned)h) << 16;
  return v.f;
}

// async global->LDS, 16 B per lane; lds base must be wave-uniform,
// lane i's data lands at lds + i*16 (m104/m108 semantics).
__device__ __forceinline__ void gload16(const void* g, void* l) {
  __builtin_amdgcn_global_load_lds((__attribute__((address_space(1))) void*)g,
                                   (__attribute__((address_space(3))) void*)l, 16, 0, 0);
}

__device__ __forceinline__ float fast_tanh(float x) {
  float a = fabsf(x);
  float e = __expf(-2.f * a);                       // in (0,1]
  float th = (1.f - e) * __builtin_amdgcn_rcpf(1.f + e);
  return copysignf(th, x);
}
__device__ __forceinline__ float fast_sigmoid(float x) {
  return __builtin_amdgcn_rcpf(1.f + __expf(-x));
}

// ---------------------------------------------------------------------------
// Weight repack:
//  wconv [L][512][256][3] fp32 -> Wb [L][3][4 yblk][128 row][256 c] bf16,
//    rows pre-interleaved into the conv kernel's gate-pairing order:
//    ch(y,row) = y*64 + ((row>>5)<<4) + (row&15) + (((row>>4)&1)<<8)
//  wout [L][256][256] fp32 -> Wob same layout bf16
// ---------------------------------------------------------------------------
__global__ void repack_w(const float* __restrict__ wc, const float* __restrict__ wo,
                         unsigned short* __restrict__ Wb, unsigned short* __restrict__ Wob) {
  size_t g = (size_t)blockIdx.x * 256 + threadIdx.x;
  const size_t NA = (size_t)LAYERS * 3 * 4 * 128 * 256;
  if (g < NA) {
    int c   = (int)(g & 255);
    int row = (int)((g >> 8) & 127);
    int y   = (int)((g >> 15) & 3);
    int lt  = (int)(g >> 17);           // l*3 + tap
    int tap = lt % 3, l = lt / 3;
    int ch = y * 64 + ((row >> 5) << 4) + (row & 15) + (((row >> 4) & 1) << 8);
    Wb[g] = f2b(wc[(((size_t)l * 512 + ch) * 256 + c) * 3 + tap]);
  } else {
    size_t g2 = g - NA;
    if (g2 < (size_t)LAYERS * 256 * 256) Wob[g2] = f2b(wo[g2]);
  }
}

// ---------------------------------------------------------------------------
// Zero the causal pad rows of xTb (workspace is poisoned to 0xAA each call).
// ---------------------------------------------------------------------------
__global__ void zero_pads(unsigned short* __restrict__ xTb) {
  size_t off = (size_t)blockIdx.y * TROWS * CCH;
  int i = blockIdx.x * 256 + threadIdx.x;     // 128*256 = 32768 threads * 16 B = 512 KB
  ulonglong2 z; z.x = 0ull; z.y = 0ull;
  ((ulonglong2*)(xTb + off))[i] = z;
}

// ---------------------------------------------------------------------------
// Transpose input [B][C][T] fp32 -> xT [B][T][C] fp32  AND  xTb bf16 (padded)
// ---------------------------------------------------------------------------
__global__ void transpose_in(const float* __restrict__ in, float* __restrict__ xT,
                             unsigned short* __restrict__ xTb) {
  __shared__ float tile[32][33];
  const int tid = threadIdx.x;
  const int t0 = blockIdx.x * 32, c0 = blockIdx.y * 32, b = blockIdx.z;
#pragma unroll
  for (int q = 0; q < 4; ++q) {
    int e = tid + 256 * q; int r = e >> 5, cc = e & 31;   // r = c-local, cc = t-local
    tile[r][cc] = in[((size_t)b * CCH + c0 + r) * TLEN + t0 + cc];
  }
  __syncthreads();
#pragma unroll
  for (int q = 0; q < 4; ++q) {
    int e = tid + 256 * q; int r = e >> 5, cc = e & 31;   // r = t-local, cc = c-local
    float v = tile[cc][r];
    xT[((size_t)b * TLEN + t0 + r) * CCH + c0 + cc] = v;
    xTb[((size_t)b * TROWS + TPAD + t0 + r) * CCH + c0 + cc] = f2b(v);
  }
}

// ---------------------------------------------------------------------------
// Final: out[B][C][T] = xT[B][T][C] + hT(bf16)[B][T][C]   (last layer residual)
// ---------------------------------------------------------------------------
__global__ void final_addT(const float* __restrict__ xT, const unsigned short* __restrict__ hT,
                           float* __restrict__ out) {
  __shared__ float tile[32][33];
  const int tid = threadIdx.x;
  const int t0 = blockIdx.x * 32, c0 = blockIdx.y * 32, b = blockIdx.z;
#pragma unroll
  for (int q = 0; q < 4; ++q) {
    int e = tid + 256 * q; int r = e >> 5, cc = e & 31;   // r = t-local, cc = c-local
    size_t idx = ((size_t)b * TLEN + t0 + r) * CCH + c0 + cc;
    tile[r][cc] = xT[idx] + b2f(hT[idx]);
  }
  __syncthreads();
#pragma unroll
  for (int q = 0; q < 4; ++q) {
    int e = tid + 256 * q; int r = e >> 5, cc = e & 31;   // r = c-local, cc = t-local
    out[((size_t)b * CCH + c0 + r) * TLEN + t0 + cc] = tile[cc][r];
  }
}

// ---------------------------------------------------------------------------
// Dilated causal conv + gate.  Z^T tile (m=time, n=channel), K = 3*256.
// A from xTb (bf16, zero-padded rows -> no causal predicate), B from
// pre-interleaved Wb.  2-phase depth-1 pipelined staging (T3 minimum):
// {ds_read frags(cur) ; issue gload(next -> cur^1) ; MFMA ; barrier}
// One barrier per K-chunk; stage latency hides under frag reads + MFMA.
// ---------------------------------------------------------------------------
__global__ __launch_bounds__(256)
void conv_gate_kernel(const unsigned short* __restrict__ xTb, // [B][TROWS][C] bf16
                      const unsigned short* __restrict__ Wl,  // [3][4][128][256] bf16, this layer
                      const float* __restrict__ bias,         // [512] fp32
                      unsigned short* __restrict__ hT,        // [B][T][C] bf16
                      float* __restrict__ skip,               // [B][C][T] fp32, this layer
                      int d) {
  __shared__ unsigned short As[2][128 * 32];  // [m=t][k], rows 64 B, unpadded (gload16)
  __shared__ unsigned short Bs[2][128 * 32];  // [n=row][k]

  const int tid  = threadIdx.x;
  const int lane = tid & 63;
  const int wv   = tid >> 6;
  const int wm   = wv & 1, wn = wv >> 1;
  const int col  = lane & 15, quad = lane >> 4;

  const int t0 = blockIdx.x * 128;
  const int y  = blockIdx.y;            // 64 gated channels per y
  const int o0 = y * 64;
  const int b  = blockIdx.z;

  const int rl = lane >> 2;             // staging row within 16-row chunk
  const int kl = (lane & 3) * 8;        // staging k-offset (shorts)
  const int ch0 = wv * 2;               // this wave's first 16-row chunk

  const unsigned short* Arow = xTb + ((size_t)b * TROWS + TPAD + t0) * CCH;

  f32x4 acc[4][4];
  const f32x4 zero = {0.f, 0.f, 0.f, 0.f};
#pragma unroll
  for (int i = 0; i < 4; ++i)
#pragma unroll
    for (int j = 0; j < 4; ++j) acc[i][j] = zero;

  const int NCHUNK = 24;                // 3 taps * 8 c0-chunks, chunk -> buf (chunk&1)

  auto stage = [&](int idx, int buf) {
    const int tap = idx >> 3;
    const int c0  = (idx & 7) << 5;
    const unsigned short* Ab = Arow - (size_t)((2 - tap) * d) * CCH;  // causal shift x[t-s]
    const unsigned short* Wb = Wl + ((size_t)tap * 4 + y) * (128 * 256);
    gload16(Ab + (size_t)(ch0 * 16      + rl) * CCH + c0 + kl, &As[buf][ ch0      * 512]);
    gload16(Ab + (size_t)(ch0 * 16 + 16 + rl) * CCH + c0 + kl, &As[buf][(ch0 + 1) * 512]);
    gload16(Wb + (size_t)(ch0 * 16      + rl) * 256 + c0 + kl, &Bs[buf][ ch0      * 512]);
    gload16(Wb + (size_t)(ch0 * 16 + 16 + rl) * 256 + c0 + kl, &Bs[buf][(ch0 + 1) * 512]);
  };

  auto step = [&](int buf, int next_idx) {
    const int k0 = quad * 8;
    bf16x8 af[4], bfv[4];
#pragma unroll
    for (int mf = 0; mf < 4; ++mf)
      af[mf] = *(const bf16x8*)&As[buf][(wm * 64 + mf * 16 + col) * 32 + k0];
#pragma unroll
    for (int nf = 0; nf < 4; ++nf)
      bfv[nf] = *(const bf16x8*)&Bs[buf][(wn * 64 + nf * 16 + col) * 32 + k0];
    if (next_idx < NCHUNK) stage(next_idx, buf ^ 1);   // prefetch overlaps MFMA below
#pragma unroll
    for (int mf = 0; mf < 4; ++mf)
#pragma unroll
      for (int nf = 0; nf < 4; ++nf)
        acc[mf][nf] = __builtin_amdgcn_mfma_f32_16x16x32_bf16(af[mf], bfv[nf], acc[mf][nf], 0, 0, 0);
  };

  stage(0, 0);
  __syncthreads();
#pragma unroll 1
  for (int i = 0; i < NCHUNK; i += 2) {
    step(0, i + 1); __syncthreads();
    step(1, i + 2); __syncthreads();
  }

  // ---- epilogue: bias, gate, store hT (bf16, [t][c]) and skip (fp32, [c][t])
#pragma unroll
  for (int mf = 0; mf < 4; ++mf) {
    const int tb = t0 + wm * 64 + mf * 16 + quad * 4;
#pragma unroll
    for (int p = 0; p < 2; ++p) {
      const int pair = wn * 2 + p;
      const int ch = o0 + pair * 16 + col;       // gated output channel (0..255)
      const float btop = bias[ch];
      const float bbot = bias[ch + 256];
      f32x4 zt = acc[mf][2 * p];
      f32x4 zb = acc[mf][2 * p + 1];
      float hr[4];
#pragma unroll
      for (int r = 0; r < 4; ++r) {
        float h = fast_tanh(zt[r] + btop) * fast_sigmoid(zb[r] + bbot);
        hr[r] = h;
        hT[((size_t)b * TLEN + tb + r) * CCH + ch] = f2b(h);
      }
      float4 hv; hv.x = hr[0]; hv.y = hr[1]; hv.z = hr[2]; hv.w = hr[3];
      *(float4*)&skip[((size_t)b * CCH + ch) * TLEN + tb] = hv;
    }
  }
}

// ---------------------------------------------------------------------------
// 1x1 transform + residual (in-place on xT, also refreshes bf16 copy xTb):
//   xT[b][t][o] += sum_c Wo[o][c] * h[b][t][c] + bout[o]
// Same 2-phase depth-1 pipelined staging as conv_gate_kernel.
// ---------------------------------------------------------------------------
__global__ __launch_bounds__(256)
void onexone_kernel(const unsigned short* __restrict__ hT,  // [B][T][C] bf16
                    const unsigned short* __restrict__ Wo,  // [256][256] bf16, this layer
                    const float* __restrict__ bias,         // [256]
                    float* __restrict__ xT,                 // [B][T][C] fp32, in-place
                    unsigned short* __restrict__ xTb) {     // [B][TROWS][C] bf16
  __shared__ unsigned short As[2][128 * 32];
  __shared__ unsigned short Bs[2][128 * 32];

  const int tid  = threadIdx.x;
  const int lane = tid & 63;
  const int wv   = tid >> 6;
  const int wm   = wv & 1, wn = wv >> 1;
  const int col  = lane & 15, quad = lane >> 4;

  const int t0 = blockIdx.x * 128;
  const int o0 = blockIdx.y * 128;
  const int b  = blockIdx.z;

  const int rl = lane >> 2;
  const int kl = (lane & 3) * 8;
  const int ch0 = wv * 2;

  const unsigned short* Ab = hT + (size_t)b * TLEN * CCH + (size_t)t0 * CCH;
  const unsigned short* Wb = Wo + (size_t)o0 * 256;

  f32x4 acc[4][4];
  const f32x4 zero = {0.f, 0.f, 0.f, 0.f};
#pragma unroll
  for (int i = 0; i < 4; ++i)
#pragma unroll
    for (int j = 0; j < 4; ++j) acc[i][j] = zero;

  const int NCHUNK = 8;                 // K=256 in 32-wide chunks

  auto stage = [&](int idx, int buf) {
    const int c0 = idx << 5;
    gload16(Ab + (size_t)(ch0 * 16      + rl) * CCH + c0 + kl, &As[buf][ ch0      * 512]);
    gload16(Ab + (size_t)(ch0 * 16 + 16 + rl) * CCH + c0 + kl, &As[buf][(ch0 + 1) * 512]);
    gload16(Wb + (size_t)(ch0 * 16      + rl) * 256 + c0 + kl, &Bs[buf][ ch0      * 512]);
    gload16(Wb + (size_t)(ch0 * 16 + 16 + rl) * 256 + c0 + kl, &Bs[buf][(ch0 + 1) * 512]);
  };

  auto step = [&](int buf, int next_idx) {
    const int k0 = quad * 8;
    bf16x8 af[4], bfv[4];
#pragma unroll
    for (int mf = 0; mf < 4; ++mf)
      af[mf] = *(const bf16x8*)&As[buf][(wm * 64 + mf * 16 + col) * 32 + k0];
#pragma unroll
    for (int nf = 0; nf < 4; ++nf)
      bfv[nf] = *(const bf16x8*)&Bs[buf][(wn * 64 + nf * 16 + col) * 32 + k0];
    if (next_idx < NCHUNK) stage(next_idx, buf ^ 1);
#pragma unroll
    for (int mf = 0; mf < 4; ++mf)
#pragma unroll
      for (int nf = 0; nf < 4; ++nf)
        acc[mf][nf] = __builtin_amdgcn_mfma_f32_16x16x32_bf16(af[mf], bfv[nf], acc[mf][nf], 0, 0, 0);
  };

  stage(0, 0);
  __syncthreads();
#pragma unroll 1
  for (int i = 0; i < NCHUNK; i += 2) {
    step(0, i + 1); __syncthreads();
    step(1, i + 2); __syncthreads();
  }

#pragma unroll
  for (int mf = 0; mf < 4; ++mf) {
    const int tb = t0 + wm * 64 + mf * 16 + quad * 4;
#pragma unroll
    for (int nf = 0; nf < 4; ++nf) {
      const int ch = o0 + wn * 64 + nf * 16 + col;
      const float bo = bias[ch];
#pragma unroll
      for (int r = 0; r < 4; ++r) {
        size_t idx = ((size_t)b * TLEN + tb + r) * CCH + ch;
        float nv = xT[idx] + acc[mf][nf][r] + bo;
        xT[idx] = nv;
        xTb[((size_t)b * TROWS + TPAD + tb + r) * CCH + ch] = f2b(nv);
      }
    }
  }
}

// ---------------------------------------------------------------------------
extern "C" void kernel_launch(void* const* d_in, const int* in_sizes, int n_in,
                              void* d_out, int out_size, void* d_ws, size_t ws_size,
                              hipStream_t stream) {
  const float* input = (const float*)d_in[0];
  const float* wconv = (const float*)d_in[1];
  const float* bconv = (const float*)d_in[2];
  const float* wout  = (const float*)d_in[3];
  const float* bout  = (const float*)d_in[4];
  float* out   = (float*)d_out;
  float* skips = out + (size_t)BCT;        // [L][B][C][T]

  char* ws = (char*)d_ws;
  float*          xT  = (float*)ws;                                    // BCT fp32
  unsigned short* xTb = (unsigned short*)(ws + (size_t)BCT * 4);       // B*TROWS*C bf16
  unsigned short* hT  = (unsigned short*)(ws + (size_t)BCT * 4
                                             + (size_t)BATCH * TROWS * CCH * 2);
  unsigned short* Wb  = hT + (size_t)BCT;                              // L*3*4*128*256
  unsigned short* Wob = Wb + (size_t)LAYERS * 3 * 512 * 256;           // L*256*256

  static const int dil[LAYERS] = {1, 2, 4, 8, 16, 32, 64, 128, 256, 512};

  repack_w<<<17920, 256, 0, stream>>>(wconv, wout, Wb, Wob);
  zero_pads<<<dim3(128, BATCH), 256, 0, stream>>>(xTb);
  transpose_in<<<dim3(TLEN / 32, CCH / 32, BATCH), 256, 0, stream>>>(input, xT, xTb);

  for (int l = 0; l < LAYERS; ++l) {
    conv_gate_kernel<<<dim3(TLEN / 128, 4, BATCH), 256, 0, stream>>>(
        xTb, Wb + (size_t)l * 3 * 512 * 256, bconv + (size_t)l * 512,
        hT, skips + (size_t)l * BCT, dil[l]);
    if (l < LAYERS - 1) {
      onexone_kernel<<<dim3(TLEN / 128, 2, BATCH), 256, 0, stream>>>(
          hT, Wob + (size_t)l * 256 * 256, bout + (size_t)l * 256, xT, xTb);
    } else {
      final_addT<<<dim3(TLEN / 32, CCH / 32, BATCH), 256, 0, stream>>>(xT, hT, out);
    }
  }
}

// Round 2
// 981.907 us; speedup vs baseline: 1.0809x; 1.0809x over previous
//
#include <hip/hip_runtime.h>
#include <hip/hip_bf16.h>

#define BATCH 4
#define CCH 256
#define TLEN 8192
#define LAYERS 10
#define BCT (BATCH*CCH*TLEN)   // 8,388,608 elements
#define TPAD 1024              // causal zero-pad rows per batch (max shift = 2*512)
#define TROWS (TPAD + TLEN)    // 9216

typedef __attribute__((ext_vector_type(8))) short bf16x8;
typedef __attribute__((ext_vector_type(4))) float f32x4;

__device__ __forceinline__ unsigned short f2b(float f) {
  union { float f; unsigned u; } v; v.f = f;
  unsigned r = (v.u + 0x7FFFu + ((v.u >> 16) & 1u)) >> 16;
  return (unsigned short)r;
}
__device__ __forceinline__ float b2f(unsigned short h) {
  union { unsigned u; float f; } v; v.u = ((unsigned)h) << 16;
  return v.f;
}

// async global->LDS, 16 B per lane; lds base must be wave-uniform,
// lane i's data lands at lds + i*16 (m104/m108 semantics).
__device__ __forceinline__ void gload16(const void* g, void* l) {
  __builtin_amdgcn_global_load_lds((__attribute__((address_space(1))) void*)g,
                                   (__attribute__((address_space(3))) void*)l, 16, 0, 0);
}

__device__ __forceinline__ float fast_tanh(float x) {
  float a = fabsf(x);
  float e = __expf(-2.f * a);                       // in (0,1]
  float th = (1.f - e) * __builtin_amdgcn_rcpf(1.f + e);
  return copysignf(th, x);
}
__device__ __forceinline__ float fast_sigmoid(float x) {
  return __builtin_amdgcn_rcpf(1.f + __expf(-x));
}

// ---------------------------------------------------------------------------
// Weight repack:
//  wconv [L][512][256][3] fp32 -> Wb [L][3][2 yblk][256 row][256 c] bf16,
//    rows pre-interleaved into the conv kernel's gate-pairing order:
//    ch(y,row) = y*128 + ((row>>5)<<4) + (row&15) + (((row>>4)&1)<<8)
//    (16-row frags alternate tanh/sigmoid halves of the same 16 channels)
//  wout [L][256][256] fp32 -> Wob same layout bf16
// ---------------------------------------------------------------------------
__global__ void repack_w(const float* __restrict__ wc, const float* __restrict__ wo,
                         unsigned short* __restrict__ Wb, unsigned short* __restrict__ Wob) {
  size_t g = (size_t)blockIdx.x * 256 + threadIdx.x;
  const size_t NA = (size_t)LAYERS * 3 * 2 * 256 * 256;
  if (g < NA) {
    int c   = (int)(g & 255);
    int row = (int)((g >> 8) & 255);
    int y   = (int)((g >> 16) & 1);
    int lt  = (int)(g >> 17);           // l*3 + tap
    int tap = lt % 3, l = lt / 3;
    int ch = y * 128 + ((row >> 5) << 4) + (row & 15) + (((row >> 4) & 1) << 8);
    Wb[g] = f2b(wc[(((size_t)l * 512 + ch) * 256 + c) * 3 + tap]);
  } else {
    size_t g2 = g - NA;
    if (g2 < (size_t)LAYERS * 256 * 256) Wob[g2] = f2b(wo[g2]);
  }
}

// ---------------------------------------------------------------------------
// Zero the causal pad rows of xTb (workspace is poisoned to 0xAA each call).
// ---------------------------------------------------------------------------
__global__ void zero_pads(unsigned short* __restrict__ xTb) {
  size_t off = (size_t)blockIdx.y * TROWS * CCH;
  int i = blockIdx.x * 256 + threadIdx.x;     // 128*256 = 32768 threads * 16 B = 512 KB
  ulonglong2 z; z.x = 0ull; z.y = 0ull;
  ((ulonglong2*)(xTb + off))[i] = z;
}

// ---------------------------------------------------------------------------
// Transpose input [B][C][T] fp32 -> xT [B][T][C] fp32  AND  xTb bf16 (padded)
// ---------------------------------------------------------------------------
__global__ void transpose_in(const float* __restrict__ in, float* __restrict__ xT,
                             unsigned short* __restrict__ xTb) {
  __shared__ float tile[32][33];
  const int tid = threadIdx.x;
  const int t0 = blockIdx.x * 32, c0 = blockIdx.y * 32, b = blockIdx.z;
#pragma unroll
  for (int q = 0; q < 4; ++q) {
    int e = tid + 256 * q; int r = e >> 5, cc = e & 31;   // r = c-local, cc = t-local
    tile[r][cc] = in[((size_t)b * CCH + c0 + r) * TLEN + t0 + cc];
  }
  __syncthreads();
#pragma unroll
  for (int q = 0; q < 4; ++q) {
    int e = tid + 256 * q; int r = e >> 5, cc = e & 31;   // r = t-local, cc = c-local
    float v = tile[cc][r];
    xT[((size_t)b * TLEN + t0 + r) * CCH + c0 + cc] = v;
    xTb[((size_t)b * TROWS + TPAD + t0 + r) * CCH + c0 + cc] = f2b(v);
  }
}

// ---------------------------------------------------------------------------
// Final: out[B][C][T] = xT[B][T][C] + hT(bf16)[B][T][C]   (last layer residual)
// ---------------------------------------------------------------------------
__global__ void final_addT(const float* __restrict__ xT, const unsigned short* __restrict__ hT,
                           float* __restrict__ out) {
  __shared__ float tile[32][33];
  const int tid = threadIdx.x;
  const int t0 = blockIdx.x * 32, c0 = blockIdx.y * 32, b = blockIdx.z;
#pragma unroll
  for (int q = 0; q < 4; ++q) {
    int e = tid + 256 * q; int r = e >> 5, cc = e & 31;   // r = t-local, cc = c-local
    size_t idx = ((size_t)b * TLEN + t0 + r) * CCH + c0 + cc;
    tile[r][cc] = xT[idx] + b2f(hT[idx]);
  }
  __syncthreads();
#pragma unroll
  for (int q = 0; q < 4; ++q) {
    int e = tid + 256 * q; int r = e >> 5, cc = e & 31;   // r = c-local, cc = t-local
    out[((size_t)b * CCH + c0 + r) * TLEN + t0 + cc] = tile[cc][r];
  }
}

// ---------------------------------------------------------------------------
// Dilated causal conv + gate — 256x256 tile, counted-vmcnt schedule.
//   BM=256 (time) x BN=256 (weight rows) x BK=32, K = 3 taps x 256 = 24 K-tiles.
//   8 waves (2M x 4N), per-wave 128x64 output, acc[8][4] f32x4.
//   3-slot LDS rotation: compute kt from slot kt%3, stage kt+2 into (kt+2)%3
//   (== slot last read at kt-1; quiescent past the kt-head barrier).
//   Per K-tile: s_waitcnt vmcnt(4) (never 0 until tail) + 1 s_barrier +
//   two {ds_read frags; stage 2 gloads; setprio(1); 16 MFMA; setprio(0)} phases.
//   T2 swizzle: LDS 16B slot ^= (row>>1)&3 via pre-swizzled per-lane global
//   source (linear gload16 dest, rule #21) + same XOR on ds_read addresses.
// ---------------------------------------------------------------------------
__global__ __launch_bounds__(512, 2)
void conv_gate_kernel(const unsigned short* __restrict__ xTb, // [B][TROWS][C] bf16
                      const unsigned short* __restrict__ Wl,  // [3][2][256][256] bf16, this layer
                      const float* __restrict__ bias,         // [512] fp32
                      unsigned short* __restrict__ hT,        // [B][T][C] bf16
                      float* __restrict__ skip,               // [B][C][T] fp32, this layer
                      int d) {
  __shared__ __align__(16) unsigned short As[3][256 * 32];  // 48 KiB, [slot][row][32 k]
  __shared__ __align__(16) unsigned short Bs[3][256 * 32];  // 48 KiB

  const int tid  = threadIdx.x;          // 0..511
  const int lane = tid & 63;
  const int wv   = tid >> 6;             // 0..7
  const int wm   = wv & 1;               // time half (128 rows each)
  const int wn   = wv >> 1;              // 0..3: 64-weight-row quarter
  const int col  = lane & 15, quad = lane >> 4;

  // 1-D grid of 256 blocks; XCD-chunked swizzle: XCD k = bid%8 owns one (y,b)
  // pair with all 32 time-tiles co-resident (weights + halo rows stay in its L2).
  const int bid  = blockIdx.x;
  const int swzb = (bid & 7) * 32 + (bid >> 3);
  const int t0   = (swzb & 31) * 256;
  const int y    = (swzb >> 5) & 1;
  const int b    = swzb >> 6;

  const int srow  = lane >> 2;           // staging row within 16-row chunk
  const int sslot = lane & 3;            // staging 16B slot within 64B row

  const unsigned short* Arow = xTb + ((size_t)b * TROWS + TPAD + t0) * CCH;

  f32x4 acc[8][4];
  const f32x4 zero = {0.f, 0.f, 0.f, 0.f};
#pragma unroll
  for (int i = 0; i < 8; ++i)
#pragma unroll
    for (int j = 0; j < 4; ++j) acc[i][j] = zero;

  const int NT = 24;                     // 3 taps * 8 c-chunks of 32

  // stage one K-tile's A (or B) into slot: 2 gload16/thread each.
  // source slot index pre-swizzled so linear LDS dest + swizzled read match.
  auto stageA = [&](int kt, int slot) {
    const int tap = kt >> 3, c0 = (kt & 7) << 5;
    const unsigned short* Ab = Arow - (size_t)((2 - tap) * d) * CCH + c0;
#pragma unroll
    for (int j = 0; j < 2; ++j) {
      const int row = (wv * 2 + j) * 16 + srow;
      const int ss  = sslot ^ ((row >> 1) & 3);
      gload16(Ab + (size_t)row * CCH + ss * 8, &As[slot][(wv * 2 + j) * 512]);
    }
  };
  auto stageB = [&](int kt, int slot) {
    const int tap = kt >> 3, c0 = (kt & 7) << 5;
    const unsigned short* Wp = Wl + ((size_t)(tap * 2 + y)) * (256 * 256) + c0;
#pragma unroll
    for (int j = 0; j < 2; ++j) {
      const int row = (wv * 2 + j) * 16 + srow;
      const int ss  = sslot ^ ((row >> 1) & 3);
      gload16(Wp + (size_t)row * 256 + ss * 8, &Bs[slot][(wv * 2 + j) * 512]);
    }
  };

  // one K-tile: stageKt<0 -> no prefetch; vm4 -> vmcnt(4) else vmcnt(0)
  auto ktile = [&](int slot, int stageKt, bool vm4) {
    if (vm4) asm volatile("s_waitcnt vmcnt(4)" ::: "memory");
    else     asm volatile("s_waitcnt vmcnt(0)" ::: "memory");
    __builtin_amdgcn_s_barrier();
    const int pslot = (slot + 2) % 3;
    // ---- phase 0: frags (bf all, af mf0-3), prefetch A, 16 MFMA
    bf16x8 bf[4], af[4];
#pragma unroll
    for (int nf = 0; nf < 4; ++nf) {
      const int row = wn * 64 + nf * 16 + col;
      bf[nf] = *(const bf16x8*)&Bs[slot][row * 32 + ((quad ^ ((row >> 1) & 3)) << 3)];
    }
#pragma unroll
    for (int mf = 0; mf < 4; ++mf) {
      const int row = wm * 128 + mf * 16 + col;
      af[mf] = *(const bf16x8*)&As[slot][row * 32 + ((quad ^ ((row >> 1) & 3)) << 3)];
    }
    if (stageKt >= 0) stageA(stageKt, pslot);
    __builtin_amdgcn_s_setprio(1);
#pragma unroll
    for (int mf = 0; mf < 4; ++mf)
#pragma unroll
      for (int nf = 0; nf < 4; ++nf)
        acc[mf][nf] = __builtin_amdgcn_mfma_f32_16x16x32_bf16(af[mf], bf[nf], acc[mf][nf], 0, 0, 0);
    __builtin_amdgcn_s_setprio(0);
    __builtin_amdgcn_sched_barrier(0);
    // ---- phase 1: frags af mf4-7, prefetch B, 16 MFMA
#pragma unroll
    for (int mf = 0; mf < 4; ++mf) {
      const int row = wm * 128 + (mf + 4) * 16 + col;
      af[mf] = *(const bf16x8*)&As[slot][row * 32 + ((quad ^ ((row >> 1) & 3)) << 3)];
    }
    if (stageKt >= 0) stageB(stageKt, pslot);
    __builtin_amdgcn_s_setprio(1);
#pragma unroll
    for (int mf = 0; mf < 4; ++mf)
#pragma unroll
      for (int nf = 0; nf < 4; ++nf)
        acc[mf + 4][nf] = __builtin_amdgcn_mfma_f32_16x16x32_bf16(af[mf], bf[nf], acc[mf + 4][nf], 0, 0, 0);
    __builtin_amdgcn_s_setprio(0);
    // fence: all my ds_reads of this slot returned before I cross the next
    // barrier (so the kt+1 iteration's stage into this region is safe).
    asm volatile("s_waitcnt lgkmcnt(0)" ::: "memory");
    __builtin_amdgcn_sched_barrier(0);
  };

  // prologue: K-tiles 0 and 1 fully staged (load order: A,A,B,B per K-tile)
  stageA(0, 0); stageB(0, 0);
  stageA(1, 1); stageB(1, 1);

#pragma unroll 1
  for (int kt = 0; kt < 21; kt += 3) {   // kt, kt+1, kt+2 -> slots 0,1,2
    ktile(0, kt + 2, true);
    ktile(1, kt + 3, true);
    ktile(2, kt + 4, true);
  }
  ktile(0, 23, true);    // kt=21, stage last K-tile
  ktile(1, -1, true);    // kt=22: outstanding = 22's 4 + 23's 4
  ktile(2, -1, false);   // kt=23: drain tail

  // ---- epilogue: bias, gate, store hT (bf16, [t][c]) and skip (fp32, [c][t])
#pragma unroll
  for (int p = 0; p < 2; ++p) {
    const int chn = y * 128 + (wn * 2 + p) * 16 + col;   // gated channel (0..255)
    const float btop = bias[chn];
    const float bbot = bias[chn + 256];
    const size_t skipBase = ((size_t)b * CCH + chn) * TLEN;
#pragma unroll
    for (int mf = 0; mf < 8; ++mf) {
      const int tb = t0 + wm * 128 + mf * 16 + quad * 4;
      f32x4 zt = acc[mf][2 * p];
      f32x4 zb = acc[mf][2 * p + 1];
      float hr[4];
#pragma unroll
      for (int r = 0; r < 4; ++r) {
        float h = fast_tanh(zt[r] + btop) * fast_sigmoid(zb[r] + bbot);
        hr[r] = h;
        hT[((size_t)b * TLEN + tb + r) * CCH + chn] = f2b(h);
      }
      float4 hv; hv.x = hr[0]; hv.y = hr[1]; hv.z = hr[2]; hv.w = hr[3];
      *(float4*)&skip[skipBase + tb] = hv;
    }
  }
}

// ---------------------------------------------------------------------------
// 1x1 transform + residual (in-place on xT, also refreshes bf16 copy xTb):
//   xT[b][t][o] += sum_c Wo[o][c] * h[b][t][c] + bout[o]
// ---------------------------------------------------------------------------
__global__ __launch_bounds__(256)
void onexone_kernel(const unsigned short* __restrict__ hT,  // [B][T][C] bf16
                    const unsigned short* __restrict__ Wo,  // [256][256] bf16, this layer
                    const float* __restrict__ bias,         // [256]
                    float* __restrict__ xT,                 // [B][T][C] fp32, in-place
                    unsigned short* __restrict__ xTb) {     // [B][TROWS][C] bf16
  __shared__ unsigned short As[2][128 * 32];
  __shared__ unsigned short Bs[2][128 * 32];

  const int tid  = threadIdx.x;
  const int lane = tid & 63;
  const int wv   = tid >> 6;
  const int wm   = wv & 1, wn = wv >> 1;
  const int col  = lane & 15, quad = lane >> 4;

  const int t0 = blockIdx.x * 128;
  const int o0 = blockIdx.y * 128;
  const int b  = blockIdx.z;

  const int rl = lane >> 2;
  const int kl = (lane & 3) * 8;
  const int ch0 = wv * 2;

  const unsigned short* Ab = hT + (size_t)b * TLEN * CCH + (size_t)t0 * CCH;
  const unsigned short* Wb = Wo + (size_t)o0 * 256;

  f32x4 acc[4][4];
  const f32x4 zero = {0.f, 0.f, 0.f, 0.f};
#pragma unroll
  for (int i = 0; i < 4; ++i)
#pragma unroll
    for (int j = 0; j < 4; ++j) acc[i][j] = zero;

  const int NCHUNK = 8;                 // K=256 in 32-wide chunks

  auto stage = [&](int idx, int buf) {
    const int c0 = idx << 5;
    gload16(Ab + (size_t)(ch0 * 16      + rl) * CCH + c0 + kl, &As[buf][ ch0      * 512]);
    gload16(Ab + (size_t)(ch0 * 16 + 16 + rl) * CCH + c0 + kl, &As[buf][(ch0 + 1) * 512]);
    gload16(Wb + (size_t)(ch0 * 16      + rl) * 256 + c0 + kl, &Bs[buf][ ch0      * 512]);
    gload16(Wb + (size_t)(ch0 * 16 + 16 + rl) * 256 + c0 + kl, &Bs[buf][(ch0 + 1) * 512]);
  };

  auto step = [&](int buf, int next_idx) {
    const int k0 = quad * 8;
    bf16x8 af[4], bfv[4];
#pragma unroll
    for (int mf = 0; mf < 4; ++mf)
      af[mf] = *(const bf16x8*)&As[buf][(wm * 64 + mf * 16 + col) * 32 + k0];
#pragma unroll
    for (int nf = 0; nf < 4; ++nf)
      bfv[nf] = *(const bf16x8*)&Bs[buf][(wn * 64 + nf * 16 + col) * 32 + k0];
    if (next_idx < NCHUNK) stage(next_idx, buf ^ 1);
#pragma unroll
    for (int mf = 0; mf < 4; ++mf)
#pragma unroll
      for (int nf = 0; nf < 4; ++nf)
        acc[mf][nf] = __builtin_amdgcn_mfma_f32_16x16x32_bf16(af[mf], bfv[nf], acc[mf][nf], 0, 0, 0);
  };

  stage(0, 0);
  __syncthreads();
#pragma unroll 1
  for (int i = 0; i < NCHUNK; i += 2) {
    step(0, i + 1); __syncthreads();
    step(1, i + 2); __syncthreads();
  }

#pragma unroll
  for (int mf = 0; mf < 4; ++mf) {
    const int tb = t0 + wm * 64 + mf * 16 + quad * 4;
#pragma unroll
    for (int nf = 0; nf < 4; ++nf) {
      const int ch = o0 + wn * 64 + nf * 16 + col;
      const float bo = bias[ch];
#pragma unroll
      for (int r = 0; r < 4; ++r) {
        size_t idx = ((size_t)b * TLEN + tb + r) * CCH + ch;
        float nv = xT[idx] + acc[mf][nf][r] + bo;
        xT[idx] = nv;
        xTb[((size_t)b * TROWS + TPAD + tb + r) * CCH + ch] = f2b(nv);
      }
    }
  }
}

// ---------------------------------------------------------------------------
extern "C" void kernel_launch(void* const* d_in, const int* in_sizes, int n_in,
                              void* d_out, int out_size, void* d_ws, size_t ws_size,
                              hipStream_t stream) {
  const float* input = (const float*)d_in[0];
  const float* wconv = (const float*)d_in[1];
  const float* bconv = (const float*)d_in[2];
  const float* wout  = (const float*)d_in[3];
  const float* bout  = (const float*)d_in[4];
  float* out   = (float*)d_out;
  float* skips = out + (size_t)BCT;        // [L][B][C][T]

  char* ws = (char*)d_ws;
  float*          xT  = (float*)ws;                                    // BCT fp32
  unsigned short* xTb = (unsigned short*)(ws + (size_t)BCT * 4);       // B*TROWS*C bf16
  unsigned short* hT  = (unsigned short*)(ws + (size_t)BCT * 4
                                             + (size_t)BATCH * TROWS * CCH * 2);
  unsigned short* Wb  = hT + (size_t)BCT;                              // L*3*2*256*256
  unsigned short* Wob = Wb + (size_t)LAYERS * 3 * 512 * 256;           // L*256*256

  static const int dil[LAYERS] = {1, 2, 4, 8, 16, 32, 64, 128, 256, 512};

  repack_w<<<17920, 256, 0, stream>>>(wconv, wout, Wb, Wob);
  zero_pads<<<dim3(128, BATCH), 256, 0, stream>>>(xTb);
  transpose_in<<<dim3(TLEN / 32, CCH / 32, BATCH), 256, 0, stream>>>(input, xT, xTb);

  for (int l = 0; l < LAYERS; ++l) {
    conv_gate_kernel<<<256, 512, 0, stream>>>(
        xTb, Wb + (size_t)l * 3 * 512 * 256, bconv + (size_t)l * 512,
        hT, skips + (size_t)l * BCT, dil[l]);
    if (l < LAYERS - 1) {
      onexone_kernel<<<dim3(TLEN / 128, 2, BATCH), 256, 0, stream>>>(
          hT, Wob + (size_t)l * 256 * 256, bout + (size_t)l * 256, xT, xTb);
    } else {
      final_addT<<<dim3(TLEN / 32, CCH / 32, BATCH), 256, 0, stream>>>(xT, hT, out);
    }
  }
}